// Round 1
// baseline (279.824 us; speedup 1.0000x reference)
//
#include <hip/hip_runtime.h>

#define N_CELLS 100000
#define IN_CH 64
#define N_EDGES 1280000

// Kernel 1: per-cell scores  s_src[n] = dot(x[n], w[0:64]),  s_tgt[n] = dot(x[n], w[64:128])
__global__ void __launch_bounds__(256) score_kernel(
    const float* __restrict__ x, const float* __restrict__ w,
    float* __restrict__ s_src, float* __restrict__ s_tgt, int n_cells) {
    int gid  = blockIdx.x * blockDim.x + threadIdx.x;
    int cell = gid >> 6;
    int lane = threadIdx.x & 63;
    if (cell >= n_cells) return;
    float xv = x[(long)cell * IN_CH + lane];
    float a = xv * w[lane];
    float b = xv * w[IN_CH + lane];
#pragma unroll
    for (int off = 32; off; off >>= 1) {
        a += __shfl_xor(a, off, 64);
        b += __shfl_xor(b, off, 64);
    }
    if (lane == 0) {
        s_src[cell] = a;
        s_tgt[cell] = b;
    }
}

__device__ __forceinline__ int lower_bound_i(const int* __restrict__ a, int n, int key) {
    int lo = 0, hi = n;
    while (lo < hi) {
        int mid = (lo + hi) >> 1;
        if (a[mid] < key) lo = mid + 1; else hi = mid;
    }
    return lo;
}

__device__ __forceinline__ float elu_f(float t) {
    return t > 0.f ? t : expm1f(t);
}

// Kernel 2: one wave per output cell; lane = channel. target_index is sorted,
// so each cell's edges are a contiguous range -> register accumulate, no atomics.
__global__ void __launch_bounds__(256) agg_kernel(
    const float* __restrict__ x, const float* __restrict__ nbhd,
    const int* __restrict__ tgt, const int* __restrict__ src,
    const float* __restrict__ s_src, const float* __restrict__ s_tgt,
    float* __restrict__ out, int n_cells, int n_edges) {
    int gid  = blockIdx.x * blockDim.x + threadIdx.x;
    int cell = gid >> 6;
    int lane = threadIdx.x & 63;
    if (cell >= n_cells) return;

    // wave-uniform binary search for this cell's edge range
    int lo = lower_bound_i(tgt, n_edges, cell);
    int hi = lower_bound_i(tgt, n_edges, cell + 1);

    float sti = s_tgt[cell];
    float acc = 0.f;
    int e = lo;
    // 2-way unroll: two independent gathers in flight per iteration
    for (; e + 2 <= hi; e += 2) {
        int   j0 = src[e],     j1 = src[e + 1];
        float n0 = nbhd[e],    n1 = nbhd[e + 1];
        float x0 = x[(long)j0 * IN_CH + lane];
        float x1 = x[(long)j1 * IN_CH + lane];
        float v0 = n0 * elu_f(s_src[j0] + sti);
        float v1 = n1 * elu_f(s_src[j1] + sti);
        acc = fmaf(v0, x0, acc);
        acc = fmaf(v1, x1, acc);
    }
    if (e < hi) {
        int j0 = src[e];
        float v0 = nbhd[e] * elu_f(s_src[j0] + sti);
        acc = fmaf(v0, x[(long)j0 * IN_CH + lane], acc);
    }
    out[(long)cell * IN_CH + lane] = acc;
}

extern "C" void kernel_launch(void* const* d_in, const int* in_sizes, int n_in,
                              void* d_out, int out_size, void* d_ws, size_t ws_size,
                              hipStream_t stream) {
    const float* x    = (const float*)d_in[0];   // [N_CELLS, 64]
    const float* w    = (const float*)d_in[1];   // [128]
    const float* nbhd = (const float*)d_in[2];   // [N_EDGES]
    const int*   tgt  = (const int*)d_in[3];     // [N_EDGES] sorted
    const int*   src  = (const int*)d_in[4];     // [N_EDGES]
    float*       out  = (float*)d_out;           // [N_CELLS, 64]

    float* s_src = (float*)d_ws;                 // N_CELLS floats
    float* s_tgt = s_src + N_CELLS;              // N_CELLS floats

    {
        int threads = 256;                       // 4 waves/block, 1 cell/wave
        int blocks  = (N_CELLS * 64 + threads - 1) / threads;
        score_kernel<<<blocks, threads, 0, stream>>>(x, w, s_src, s_tgt, N_CELLS);
    }
    {
        int threads = 256;
        int blocks  = (N_CELLS * 64 + threads - 1) / threads;
        agg_kernel<<<blocks, threads, 0, stream>>>(x, nbhd, tgt, src, s_src, s_tgt,
                                                   out, N_CELLS, N_EDGES);
    }
}

// Round 2
// 80.010 us; speedup vs baseline: 3.4974x; 3.4974x over previous
//
#include <hip/hip_runtime.h>

#define N_CELLS 100000
#define IN_CH 64
#define N_EDGES 1280000

// Kernel 1: per-cell scores  s_src[n] = dot(x[n], w[0:64]),  s_tgt[n] = dot(x[n], w[64:128])
__global__ void __launch_bounds__(256) score_kernel(
    const float* __restrict__ x, const float* __restrict__ w,
    float* __restrict__ s_src, float* __restrict__ s_tgt, int n_cells) {
    int gid  = blockIdx.x * blockDim.x + threadIdx.x;
    int cell = gid >> 6;
    int lane = threadIdx.x & 63;
    if (cell >= n_cells) return;
    float xv = x[((unsigned)cell << 6) | lane];
    float a = xv * w[lane];
    float b = xv * w[IN_CH + lane];
#pragma unroll
    for (int off = 32; off; off >>= 1) {
        a += __shfl_xor(a, off, 64);
        b += __shfl_xor(b, off, 64);
    }
    if (lane == 0) {
        s_src[cell] = a;
        s_tgt[cell] = b;
    }
}

// Kernel 2 (edge-parallel): per-edge attention value + CSR row offsets from sorted tgt.
// row_start[c] = first edge e with tgt[e] >= c   (lower bound), row_start[n_cells] = n_edges.
__global__ void __launch_bounds__(256) edge_kernel(
    const float* __restrict__ nbhd, const int* __restrict__ tgt,
    const int* __restrict__ src,
    const float* __restrict__ s_src, const float* __restrict__ s_tgt,
    int* __restrict__ row_start, float* __restrict__ vals,
    int n_edges, int n_cells) {
    int e = blockIdx.x * blockDim.x + threadIdx.x;
    if (e >= n_edges) return;
    int t = tgt[e];
    float a = s_src[src[e]] + s_tgt[t];
    vals[e] = nbhd[e] * (a > 0.f ? a : expm1f(a));
    int prev = (e == 0) ? -1 : tgt[e - 1];
    for (int c = prev + 1; c <= t; ++c) row_start[c] = e;
    if (e == n_edges - 1) {
        for (int c = t + 1; c <= n_cells; ++c) row_start[c] = n_edges;
    }
}

// Kernel 3: one wave per output cell; lane = channel. Edge range from CSR offsets.
// Wave vector-loads 64 edges' (src, val) at once, broadcasts via shfl, 4-deep gather unroll.
__global__ void __launch_bounds__(256) agg_kernel(
    const float* __restrict__ x, const int* __restrict__ src,
    const float* __restrict__ vals, const int* __restrict__ row_start,
    float* __restrict__ out, int n_cells) {
    int gid  = blockIdx.x * blockDim.x + threadIdx.x;
    int cell = gid >> 6;
    int lane = threadIdx.x & 63;
    if (cell >= n_cells) return;

    int lo = row_start[cell];
    int hi = row_start[cell + 1];

    float acc = 0.f;
    for (int base = lo; base < hi; base += 64) {
        int cnt = hi - base;
        if (cnt > 64) cnt = 64;
        int   j = 0;
        float v = 0.f;
        if (lane < cnt) {
            j = src[base + lane];
            v = vals[base + lane];
        }
        int t = 0;
        for (; t + 4 <= cnt; t += 4) {
            int   j0 = __shfl(j, t, 64),     j1 = __shfl(j, t + 1, 64);
            int   j2 = __shfl(j, t + 2, 64), j3 = __shfl(j, t + 3, 64);
            float v0 = __shfl(v, t, 64),     v1 = __shfl(v, t + 1, 64);
            float v2 = __shfl(v, t + 2, 64), v3 = __shfl(v, t + 3, 64);
            float x0 = x[((unsigned)j0 << 6) | lane];
            float x1 = x[((unsigned)j1 << 6) | lane];
            float x2 = x[((unsigned)j2 << 6) | lane];
            float x3 = x[((unsigned)j3 << 6) | lane];
            acc = fmaf(v0, x0, acc);
            acc = fmaf(v1, x1, acc);
            acc = fmaf(v2, x2, acc);
            acc = fmaf(v3, x3, acc);
        }
        for (; t < cnt; ++t) {
            int   jt = __shfl(j, t, 64);
            float vt = __shfl(v, t, 64);
            acc = fmaf(vt, x[((unsigned)jt << 6) | lane], acc);
        }
    }
    out[((unsigned)cell << 6) | lane] = acc;
}

extern "C" void kernel_launch(void* const* d_in, const int* in_sizes, int n_in,
                              void* d_out, int out_size, void* d_ws, size_t ws_size,
                              hipStream_t stream) {
    const float* x    = (const float*)d_in[0];   // [N_CELLS, 64]
    const float* w    = (const float*)d_in[1];   // [128]
    const float* nbhd = (const float*)d_in[2];   // [N_EDGES]
    const int*   tgt  = (const int*)d_in[3];     // [N_EDGES] sorted
    const int*   src  = (const int*)d_in[4];     // [N_EDGES]
    float*       out  = (float*)d_out;           // [N_CELLS, 64]

    // workspace layout (floats/ints, 4B each): 6.32 MB total
    float* s_src     = (float*)d_ws;               // N_CELLS
    float* s_tgt     = s_src + N_CELLS;            // N_CELLS
    int*   row_start = (int*)(s_tgt + N_CELLS);    // N_CELLS + 1
    float* vals      = (float*)(row_start + N_CELLS + 1);  // N_EDGES

    {
        int threads = 256;
        int blocks  = (N_CELLS * 64 + threads - 1) / threads;
        score_kernel<<<blocks, threads, 0, stream>>>(x, w, s_src, s_tgt, N_CELLS);
    }
    {
        int threads = 256;
        int blocks  = (N_EDGES + threads - 1) / threads;
        edge_kernel<<<blocks, threads, 0, stream>>>(nbhd, tgt, src, s_src, s_tgt,
                                                    row_start, vals, N_EDGES, N_CELLS);
    }
    {
        int threads = 256;
        int blocks  = (N_CELLS * 64 + threads - 1) / threads;
        agg_kernel<<<blocks, threads, 0, stream>>>(x, src, vals, row_start, out, N_CELLS);
    }
}

// Round 3
// 65.399 us; speedup vs baseline: 4.2787x; 1.2234x over previous
//
#include <hip/hip_runtime.h>

#define N_CELLS 100000
#define IN_CH 64
#define N_EDGES 1280000

// Kernel 1: per-cell scores. One wave = 4 cells; 16 lanes per cell, float4 per lane.
// s_src[n] = dot(x[n], w[0:64]), s_tgt[n] = dot(x[n], w[64:128])
__global__ void __launch_bounds__(256) score_kernel(
    const float* __restrict__ x, const float* __restrict__ w,
    float* __restrict__ s_src, float* __restrict__ s_tgt, int n_cells) {
    int gid  = blockIdx.x * blockDim.x + threadIdx.x;
    int wave = gid >> 6;
    int lane = threadIdx.x & 63;
    int grp  = lane >> 4;       // 0..3 -> which cell within the wave
    int sub  = lane & 15;       // 0..15 -> which float4 of the row
    int cell = wave * 4 + grp;

    float4 xv = make_float4(0.f, 0.f, 0.f, 0.f);
    if (cell < n_cells)
        xv = *(const float4*)&x[(((unsigned)cell << 6) | ((unsigned)sub << 2))];
    const float4* w4 = (const float4*)w;
    float4 wa = w4[sub];        // w[0:64]
    float4 wb = w4[16 + sub];   // w[64:128]
    float a = xv.x * wa.x + xv.y * wa.y + xv.z * wa.z + xv.w * wa.w;
    float b = xv.x * wb.x + xv.y * wb.y + xv.z * wb.z + xv.w * wb.w;
#pragma unroll
    for (int off = 8; off; off >>= 1) {
        a += __shfl_xor(a, off, 64);
        b += __shfl_xor(b, off, 64);
    }
    if (sub == 0 && cell < n_cells) {
        s_src[cell] = a;
        s_tgt[cell] = b;
    }
}

// Kernel 2: CSR row offsets from sorted tgt.
// row_start[c] = first edge e with tgt[e] >= c; row_start[n_cells] = n_edges.
__global__ void __launch_bounds__(256) rowstart_kernel(
    const int* __restrict__ tgt, int* __restrict__ row_start,
    int n_edges, int n_cells) {
    int e = blockIdx.x * blockDim.x + threadIdx.x;
    if (e >= n_edges) return;
    int t = tgt[e];
    int prev = (e == 0) ? -1 : tgt[e - 1];
    for (int c = prev + 1; c <= t; ++c) row_start[c] = e;
    if (e == n_edges - 1) {
        for (int c = t + 1; c <= n_cells; ++c) row_start[c] = n_edges;
    }
}

// Kernel 3: one wave per output cell. Wave loads 64 edges' (src, nbhd) coalesced,
// computes v = nbhd*elu(s_src[j]+s_tgt[i]) lane-parallel, then processes 4 edges
// per step (one per 16-lane group, float4 x-gather per lane), 2-way unrolled.
__global__ void __launch_bounds__(256) agg_kernel(
    const float* __restrict__ x, const int* __restrict__ src,
    const float* __restrict__ nbhd,
    const float* __restrict__ s_src, const float* __restrict__ s_tgt,
    const int* __restrict__ row_start,
    float* __restrict__ out, int n_cells) {
    int gid  = blockIdx.x * blockDim.x + threadIdx.x;
    int cell = gid >> 6;
    int lane = threadIdx.x & 63;
    if (cell >= n_cells) return;
    int grp = lane >> 4;
    int sub = lane & 15;
    unsigned suboff = (unsigned)sub << 2;

    int lo = row_start[cell];
    int hi = row_start[cell + 1];
    float sti = s_tgt[cell];

    float4 acc = make_float4(0.f, 0.f, 0.f, 0.f);
    for (int base = lo; base < hi; base += 64) {
        int cnt = hi - base;
        if (cnt > 64) cnt = 64;
        int   j = 0;
        float v = 0.f;
        if (lane < cnt) {
            j = src[base + lane];
            float a = s_src[j] + sti;
            v = nbhd[base + lane] * (a > 0.f ? a : expm1f(a));
        }
        int t = 0;
        for (; t + 8 <= cnt; t += 8) {
            int   j0 = __shfl(j, t + grp, 64);
            float v0 = __shfl(v, t + grp, 64);
            int   j1 = __shfl(j, t + 4 + grp, 64);
            float v1 = __shfl(v, t + 4 + grp, 64);
            float4 x0 = *(const float4*)&x[(((unsigned)j0 << 6) | suboff)];
            float4 x1 = *(const float4*)&x[(((unsigned)j1 << 6) | suboff)];
            acc.x = fmaf(v0, x0.x, acc.x);
            acc.y = fmaf(v0, x0.y, acc.y);
            acc.z = fmaf(v0, x0.z, acc.z);
            acc.w = fmaf(v0, x0.w, acc.w);
            acc.x = fmaf(v1, x1.x, acc.x);
            acc.y = fmaf(v1, x1.y, acc.y);
            acc.z = fmaf(v1, x1.z, acc.z);
            acc.w = fmaf(v1, x1.w, acc.w);
        }
        // remainder: groups beyond the last edge see v==0, j==0 (safe dummy load)
        for (; t < cnt; t += 4) {
            int   jt = __shfl(j, t + grp, 64);
            float vt = __shfl(v, t + grp, 64);
            float4 xt = *(const float4*)&x[(((unsigned)jt << 6) | suboff)];
            acc.x = fmaf(vt, xt.x, acc.x);
            acc.y = fmaf(vt, xt.y, acc.y);
            acc.z = fmaf(vt, xt.z, acc.z);
            acc.w = fmaf(vt, xt.w, acc.w);
        }
    }
    // reduce the 4 groups' partial sums (all lanes end with the total)
#pragma unroll
    for (int off = 16; off <= 32; off <<= 1) {
        acc.x += __shfl_xor(acc.x, off, 64);
        acc.y += __shfl_xor(acc.y, off, 64);
        acc.z += __shfl_xor(acc.z, off, 64);
        acc.w += __shfl_xor(acc.w, off, 64);
    }
    if (grp == 0)
        *(float4*)&out[(((unsigned)cell << 6) | suboff)] = acc;
}

extern "C" void kernel_launch(void* const* d_in, const int* in_sizes, int n_in,
                              void* d_out, int out_size, void* d_ws, size_t ws_size,
                              hipStream_t stream) {
    const float* x    = (const float*)d_in[0];   // [N_CELLS, 64]
    const float* w    = (const float*)d_in[1];   // [128]
    const float* nbhd = (const float*)d_in[2];   // [N_EDGES]
    const int*   tgt  = (const int*)d_in[3];     // [N_EDGES] sorted
    const int*   src  = (const int*)d_in[4];     // [N_EDGES]
    float*       out  = (float*)d_out;           // [N_CELLS, 64]

    float* s_src     = (float*)d_ws;               // N_CELLS
    float* s_tgt     = s_src + N_CELLS;            // N_CELLS
    int*   row_start = (int*)(s_tgt + N_CELLS);    // N_CELLS + 1

    {
        int threads = 256;                          // 4 waves = 16 cells / block
        int blocks  = (N_CELLS * 16 + threads - 1) / threads;
        score_kernel<<<blocks, threads, 0, stream>>>(x, w, s_src, s_tgt, N_CELLS);
    }
    {
        int threads = 256;
        int blocks  = (N_EDGES + threads - 1) / threads;
        rowstart_kernel<<<blocks, threads, 0, stream>>>(tgt, row_start, N_EDGES, N_CELLS);
    }
    {
        int threads = 256;
        int blocks  = (N_CELLS * 64 + threads - 1) / threads;
        agg_kernel<<<blocks, threads, 0, stream>>>(x, src, nbhd, s_src, s_tgt,
                                                   row_start, out, N_CELLS);
    }
}

// Round 4
// 64.448 us; speedup vs baseline: 4.3418x; 1.0148x over previous
//
#include <hip/hip_runtime.h>

#define N_CELLS 100000
#define IN_CH 64
#define N_EDGES 1280000

// Kernel 1: per-cell scores. One wave = 4 cells; 16 lanes per cell, float4 per lane.
// s_src[n] = dot(x[n], w[0:64]), s_tgt[n] = dot(x[n], w[64:128])
__global__ void __launch_bounds__(256) score_kernel(
    const float* __restrict__ x, const float* __restrict__ w,
    float* __restrict__ s_src, float* __restrict__ s_tgt, int n_cells) {
    int gid  = blockIdx.x * blockDim.x + threadIdx.x;
    int wave = gid >> 6;
    int lane = threadIdx.x & 63;
    int grp  = lane >> 4;
    int sub  = lane & 15;
    int cell = wave * 4 + grp;

    float4 xv = make_float4(0.f, 0.f, 0.f, 0.f);
    if (cell < n_cells)
        xv = *(const float4*)&x[(((unsigned)cell << 6) | ((unsigned)sub << 2))];
    const float4* w4 = (const float4*)w;
    float4 wa = w4[sub];
    float4 wb = w4[16 + sub];
    float a = xv.x * wa.x + xv.y * wa.y + xv.z * wa.z + xv.w * wa.w;
    float b = xv.x * wb.x + xv.y * wb.y + xv.z * wb.z + xv.w * wb.w;
#pragma unroll
    for (int off = 8; off; off >>= 1) {
        a += __shfl_xor(a, off, 64);
        b += __shfl_xor(b, off, 64);
    }
    if (sub == 0 && cell < n_cells) {
        s_src[cell] = a;
        s_tgt[cell] = b;
    }
}

// Kernel 2: CSR row offsets from sorted tgt (single read of tgt; prev via shfl_up).
__global__ void __launch_bounds__(256) rowstart_kernel(
    const int* __restrict__ tgt, int* __restrict__ row_start,
    int n_edges, int n_cells) {
    int e = blockIdx.x * blockDim.x + threadIdx.x;
    if (e >= n_edges) return;
    int lane = threadIdx.x & 63;
    int t = tgt[e];
    int prev = __shfl_up(t, 1, 64);
    if (lane == 0) prev = (e == 0) ? -1 : tgt[e - 1];
    for (int c = prev + 1; c <= t; ++c) row_start[c] = e;
    if (e == n_edges - 1) {
        for (int c = t + 1; c <= n_cells; ++c) row_start[c] = n_edges;
    }
}

// Kernel 3: one 16-lane group per output cell (4 cells/wave), group-independent.
// Group loads its own 16-edge window (src/nbhd coalesced), computes
// v = nbhd*elu(s_src[j]+s_tgt[i]) in-group, gathers x rows (float4/lane) with
// a 4-deep unroll -> up to 16 independent gathers in flight per wave.
__global__ void __launch_bounds__(256) agg_kernel(
    const float* __restrict__ x, const int* __restrict__ src,
    const float* __restrict__ nbhd,
    const float* __restrict__ s_src, const float* __restrict__ s_tgt,
    const int* __restrict__ row_start,
    float* __restrict__ out, int n_cells) {
    int gid  = blockIdx.x * blockDim.x + threadIdx.x;
    int lane = threadIdx.x & 63;
    int grp  = lane >> 4;
    int sub  = lane & 15;
    int cell = (gid >> 6) * 4 + grp;
    unsigned suboff = (unsigned)sub << 2;
    int gbase = grp << 4;   // first lane of this group (shfl source base)

    int lo = 0, hi = 0;
    float sti = 0.f;
    if (cell < n_cells) {
        lo  = row_start[cell];
        hi  = row_start[cell + 1];
        sti = s_tgt[cell];
    }

    float4 acc = make_float4(0.f, 0.f, 0.f, 0.f);
    for (int base = lo; base < hi; base += 16) {
        int cnt = hi - base;
        if (cnt > 16) cnt = 16;
        int   j = 0;
        float v = 0.f;
        if (sub < cnt) {
            j = src[base + sub];
            float a = s_src[j] + sti;
            v = nbhd[base + sub] * (a > 0.f ? a : expm1f(a));
        }
        int t = 0;
        for (; t + 4 <= cnt; t += 4) {
            int   j0 = __shfl(j, gbase + t,     64);
            int   j1 = __shfl(j, gbase + t + 1, 64);
            int   j2 = __shfl(j, gbase + t + 2, 64);
            int   j3 = __shfl(j, gbase + t + 3, 64);
            float v0 = __shfl(v, gbase + t,     64);
            float v1 = __shfl(v, gbase + t + 1, 64);
            float v2 = __shfl(v, gbase + t + 2, 64);
            float v3 = __shfl(v, gbase + t + 3, 64);
            float4 x0 = *(const float4*)&x[(((unsigned)j0 << 6) | suboff)];
            float4 x1 = *(const float4*)&x[(((unsigned)j1 << 6) | suboff)];
            float4 x2 = *(const float4*)&x[(((unsigned)j2 << 6) | suboff)];
            float4 x3 = *(const float4*)&x[(((unsigned)j3 << 6) | suboff)];
            acc.x = fmaf(v0, x0.x, acc.x); acc.y = fmaf(v0, x0.y, acc.y);
            acc.z = fmaf(v0, x0.z, acc.z); acc.w = fmaf(v0, x0.w, acc.w);
            acc.x = fmaf(v1, x1.x, acc.x); acc.y = fmaf(v1, x1.y, acc.y);
            acc.z = fmaf(v1, x1.z, acc.z); acc.w = fmaf(v1, x1.w, acc.w);
            acc.x = fmaf(v2, x2.x, acc.x); acc.y = fmaf(v2, x2.y, acc.y);
            acc.z = fmaf(v2, x2.z, acc.z); acc.w = fmaf(v2, x2.w, acc.w);
            acc.x = fmaf(v3, x3.x, acc.x); acc.y = fmaf(v3, x3.y, acc.y);
            acc.z = fmaf(v3, x3.z, acc.z); acc.w = fmaf(v3, x3.w, acc.w);
        }
        for (; t < cnt; ++t) {
            int   jt = __shfl(j, gbase + t, 64);
            float vt = __shfl(v, gbase + t, 64);
            float4 xt = *(const float4*)&x[(((unsigned)jt << 6) | suboff)];
            acc.x = fmaf(vt, xt.x, acc.x); acc.y = fmaf(vt, xt.y, acc.y);
            acc.z = fmaf(vt, xt.z, acc.z); acc.w = fmaf(vt, xt.w, acc.w);
        }
    }
    if (cell < n_cells)
        *(float4*)&out[(((unsigned)cell << 6) | suboff)] = acc;
}

extern "C" void kernel_launch(void* const* d_in, const int* in_sizes, int n_in,
                              void* d_out, int out_size, void* d_ws, size_t ws_size,
                              hipStream_t stream) {
    const float* x    = (const float*)d_in[0];   // [N_CELLS, 64]
    const float* w    = (const float*)d_in[1];   // [128]
    const float* nbhd = (const float*)d_in[2];   // [N_EDGES]
    const int*   tgt  = (const int*)d_in[3];     // [N_EDGES] sorted
    const int*   src  = (const int*)d_in[4];     // [N_EDGES]
    float*       out  = (float*)d_out;           // [N_CELLS, 64]

    float* s_src     = (float*)d_ws;               // N_CELLS
    float* s_tgt     = s_src + N_CELLS;            // N_CELLS
    int*   row_start = (int*)(s_tgt + N_CELLS);    // N_CELLS + 1

    {
        int threads = 256;                          // 16 cells per block
        int blocks  = (N_CELLS * 16 + threads - 1) / threads;
        score_kernel<<<blocks, threads, 0, stream>>>(x, w, s_src, s_tgt, N_CELLS);
    }
    {
        int threads = 256;
        int blocks  = (N_EDGES + threads - 1) / threads;
        rowstart_kernel<<<blocks, threads, 0, stream>>>(tgt, row_start, N_EDGES, N_CELLS);
    }
    {
        int threads = 256;                          // 16 cells per block
        int blocks  = (N_CELLS * 16 + threads - 1) / threads;
        agg_kernel<<<blocks, threads, 0, stream>>>(x, src, nbhd, s_src, s_tgt,
                                                   row_start, out, N_CELLS);
    }
}

// Round 5
// 63.074 us; speedup vs baseline: 4.4365x; 1.0218x over previous
//
#include <hip/hip_runtime.h>

#define N_CELLS 100000
#define IN_CH 64
#define N_EDGES 1280000

// ---- bf16 helpers (bit-level, RNE) ----
__device__ __forceinline__ unsigned short f32_to_bf16(float f) {
    unsigned u = __float_as_uint(f);
    u += 0x7FFFu + ((u >> 16) & 1u);   // round to nearest even
    return (unsigned short)(u >> 16);
}
__device__ __forceinline__ float bf16_to_f32(unsigned short h) {
    return __uint_as_float((unsigned)h << 16);
}

// Kernel 1: per-cell scores + fused f32->bf16 copy of x.
// One wave = 4 cells; 16 lanes per cell, float4 per lane.
__global__ void __launch_bounds__(256) score_kernel(
    const float* __restrict__ x, const float* __restrict__ w,
    float* __restrict__ s_src, float* __restrict__ s_tgt,
    unsigned short* __restrict__ xb, int n_cells) {
    int gid  = blockIdx.x * blockDim.x + threadIdx.x;
    int wave = gid >> 6;
    int lane = threadIdx.x & 63;
    int grp  = lane >> 4;
    int sub  = lane & 15;
    int cell = wave * 4 + grp;

    float4 xv = make_float4(0.f, 0.f, 0.f, 0.f);
    if (cell < n_cells)
        xv = *(const float4*)&x[(((unsigned)cell << 6) | ((unsigned)sub << 2))];
    if (xb && cell < n_cells) {
        ushort4 hb;
        hb.x = f32_to_bf16(xv.x); hb.y = f32_to_bf16(xv.y);
        hb.z = f32_to_bf16(xv.z); hb.w = f32_to_bf16(xv.w);
        *(ushort4*)&xb[(((unsigned)cell << 6) | ((unsigned)sub << 2))] = hb;
    }
    const float4* w4 = (const float4*)w;
    float4 wa = w4[sub];
    float4 wb = w4[16 + sub];
    float a = xv.x * wa.x + xv.y * wa.y + xv.z * wa.z + xv.w * wa.w;
    float b = xv.x * wb.x + xv.y * wb.y + xv.z * wb.z + xv.w * wb.w;
#pragma unroll
    for (int off = 8; off; off >>= 1) {
        a += __shfl_xor(a, off, 64);
        b += __shfl_xor(b, off, 64);
    }
    if (sub == 0 && cell < n_cells) {
        s_src[cell] = a;
        s_tgt[cell] = b;
    }
}

// Kernel 2: CSR row offsets from sorted tgt (prev via shfl_up).
__global__ void __launch_bounds__(256) rowstart_kernel(
    const int* __restrict__ tgt, int* __restrict__ row_start,
    int n_edges, int n_cells) {
    int e = blockIdx.x * blockDim.x + threadIdx.x;
    if (e >= n_edges) return;
    int lane = threadIdx.x & 63;
    int t = tgt[e];
    int prev = __shfl_up(t, 1, 64);
    if (lane == 0) prev = (e == 0) ? -1 : tgt[e - 1];
    for (int c = prev + 1; c <= t; ++c) row_start[c] = e;
    if (e == n_edges - 1) {
        for (int c = t + 1; c <= n_cells; ++c) row_start[c] = n_edges;
    }
}

// Kernel 3 (bf16 gather): one 16-lane group per cell; lane loads ushort4 (4 ch, 8 B)
// of the bf16 x row -> half the gather traffic of the f32 version. f32 accumulate.
__global__ void __launch_bounds__(256) agg_kernel_bf16(
    const unsigned short* __restrict__ xb, const int* __restrict__ src,
    const float* __restrict__ nbhd,
    const float* __restrict__ s_src, const float* __restrict__ s_tgt,
    const int* __restrict__ row_start,
    float* __restrict__ out, int n_cells) {
    int gid  = blockIdx.x * blockDim.x + threadIdx.x;
    int lane = threadIdx.x & 63;
    int grp  = lane >> 4;
    int sub  = lane & 15;
    int cell = (gid >> 6) * 4 + grp;
    unsigned suboff = (unsigned)sub << 2;
    int gbase = grp << 4;

    int lo = 0, hi = 0;
    float sti = 0.f;
    if (cell < n_cells) {
        lo  = row_start[cell];
        hi  = row_start[cell + 1];
        sti = s_tgt[cell];
    }

    float4 acc = make_float4(0.f, 0.f, 0.f, 0.f);
    for (int base = lo; base < hi; base += 16) {
        int cnt = hi - base;
        if (cnt > 16) cnt = 16;
        int   j = 0;
        float v = 0.f;
        if (sub < cnt) {
            j = src[base + sub];
            float a = s_src[j] + sti;
            v = nbhd[base + sub] * (a > 0.f ? a : expm1f(a));
        }
        int t = 0;
        for (; t + 4 <= cnt; t += 4) {
            int   j0 = __shfl(j, gbase + t,     64);
            int   j1 = __shfl(j, gbase + t + 1, 64);
            int   j2 = __shfl(j, gbase + t + 2, 64);
            int   j3 = __shfl(j, gbase + t + 3, 64);
            float v0 = __shfl(v, gbase + t,     64);
            float v1 = __shfl(v, gbase + t + 1, 64);
            float v2 = __shfl(v, gbase + t + 2, 64);
            float v3 = __shfl(v, gbase + t + 3, 64);
            ushort4 h0 = *(const ushort4*)&xb[(((unsigned)j0 << 6) | suboff)];
            ushort4 h1 = *(const ushort4*)&xb[(((unsigned)j1 << 6) | suboff)];
            ushort4 h2 = *(const ushort4*)&xb[(((unsigned)j2 << 6) | suboff)];
            ushort4 h3 = *(const ushort4*)&xb[(((unsigned)j3 << 6) | suboff)];
            acc.x = fmaf(v0, bf16_to_f32(h0.x), acc.x);
            acc.y = fmaf(v0, bf16_to_f32(h0.y), acc.y);
            acc.z = fmaf(v0, bf16_to_f32(h0.z), acc.z);
            acc.w = fmaf(v0, bf16_to_f32(h0.w), acc.w);
            acc.x = fmaf(v1, bf16_to_f32(h1.x), acc.x);
            acc.y = fmaf(v1, bf16_to_f32(h1.y), acc.y);
            acc.z = fmaf(v1, bf16_to_f32(h1.z), acc.z);
            acc.w = fmaf(v1, bf16_to_f32(h1.w), acc.w);
            acc.x = fmaf(v2, bf16_to_f32(h2.x), acc.x);
            acc.y = fmaf(v2, bf16_to_f32(h2.y), acc.y);
            acc.z = fmaf(v2, bf16_to_f32(h2.z), acc.z);
            acc.w = fmaf(v2, bf16_to_f32(h2.w), acc.w);
            acc.x = fmaf(v3, bf16_to_f32(h3.x), acc.x);
            acc.y = fmaf(v3, bf16_to_f32(h3.y), acc.y);
            acc.z = fmaf(v3, bf16_to_f32(h3.z), acc.z);
            acc.w = fmaf(v3, bf16_to_f32(h3.w), acc.w);
        }
        for (; t < cnt; ++t) {
            int   jt = __shfl(j, gbase + t, 64);
            float vt = __shfl(v, gbase + t, 64);
            ushort4 ht = *(const ushort4*)&xb[(((unsigned)jt << 6) | suboff)];
            acc.x = fmaf(vt, bf16_to_f32(ht.x), acc.x);
            acc.y = fmaf(vt, bf16_to_f32(ht.y), acc.y);
            acc.z = fmaf(vt, bf16_to_f32(ht.z), acc.z);
            acc.w = fmaf(vt, bf16_to_f32(ht.w), acc.w);
        }
    }
    if (cell < n_cells)
        *(float4*)&out[(((unsigned)cell << 6) | suboff)] = acc;
}

// Fallback f32-gather version (used only if workspace is too small for xb).
__global__ void __launch_bounds__(256) agg_kernel_f32(
    const float* __restrict__ x, const int* __restrict__ src,
    const float* __restrict__ nbhd,
    const float* __restrict__ s_src, const float* __restrict__ s_tgt,
    const int* __restrict__ row_start,
    float* __restrict__ out, int n_cells) {
    int gid  = blockIdx.x * blockDim.x + threadIdx.x;
    int lane = threadIdx.x & 63;
    int grp  = lane >> 4;
    int sub  = lane & 15;
    int cell = (gid >> 6) * 4 + grp;
    unsigned suboff = (unsigned)sub << 2;
    int gbase = grp << 4;

    int lo = 0, hi = 0;
    float sti = 0.f;
    if (cell < n_cells) {
        lo  = row_start[cell];
        hi  = row_start[cell + 1];
        sti = s_tgt[cell];
    }
    float4 acc = make_float4(0.f, 0.f, 0.f, 0.f);
    for (int base = lo; base < hi; base += 16) {
        int cnt = hi - base;
        if (cnt > 16) cnt = 16;
        int   j = 0;
        float v = 0.f;
        if (sub < cnt) {
            j = src[base + sub];
            float a = s_src[j] + sti;
            v = nbhd[base + sub] * (a > 0.f ? a : expm1f(a));
        }
        for (int t = 0; t < cnt; ++t) {
            int   jt = __shfl(j, gbase + t, 64);
            float vt = __shfl(v, gbase + t, 64);
            float4 xt = *(const float4*)&x[(((unsigned)jt << 6) | suboff)];
            acc.x = fmaf(vt, xt.x, acc.x); acc.y = fmaf(vt, xt.y, acc.y);
            acc.z = fmaf(vt, xt.z, acc.z); acc.w = fmaf(vt, xt.w, acc.w);
        }
    }
    if (cell < n_cells)
        *(float4*)&out[(((unsigned)cell << 6) | suboff)] = acc;
}

extern "C" void kernel_launch(void* const* d_in, const int* in_sizes, int n_in,
                              void* d_out, int out_size, void* d_ws, size_t ws_size,
                              hipStream_t stream) {
    const float* x    = (const float*)d_in[0];   // [N_CELLS, 64]
    const float* w    = (const float*)d_in[1];   // [128]
    const float* nbhd = (const float*)d_in[2];   // [N_EDGES]
    const int*   tgt  = (const int*)d_in[3];     // [N_EDGES] sorted
    const int*   src  = (const int*)d_in[4];     // [N_EDGES]
    float*       out  = (float*)d_out;           // [N_CELLS, 64]

    // workspace layout
    float* s_src     = (float*)d_ws;                       // N_CELLS f32
    float* s_tgt     = s_src + N_CELLS;                    // N_CELLS f32
    int*   row_start = (int*)(s_tgt + N_CELLS);            // N_CELLS+1 i32
    unsigned short* xb = (unsigned short*)(row_start + N_CELLS + 1);  // N_CELLS*64 bf16
    size_t need_bf16 = (size_t)(2 * N_CELLS + N_CELLS + 1) * 4 + (size_t)N_CELLS * IN_CH * 2;
    bool use_bf16 = ws_size >= need_bf16;

    {
        int threads = 256;
        int blocks  = (N_CELLS * 16 + threads - 1) / threads;
        score_kernel<<<blocks, threads, 0, stream>>>(x, w, s_src, s_tgt,
                                                     use_bf16 ? xb : (unsigned short*)nullptr,
                                                     N_CELLS);
    }
    {
        int threads = 256;
        int blocks  = (N_EDGES + threads - 1) / threads;
        rowstart_kernel<<<blocks, threads, 0, stream>>>(tgt, row_start, N_EDGES, N_CELLS);
    }
    {
        int threads = 256;
        int blocks  = (N_CELLS * 16 + threads - 1) / threads;
        if (use_bf16)
            agg_kernel_bf16<<<blocks, threads, 0, stream>>>(xb, src, nbhd, s_src, s_tgt,
                                                            row_start, out, N_CELLS);
        else
            agg_kernel_f32<<<blocks, threads, 0, stream>>>(x, src, nbhd, s_src, s_tgt,
                                                           row_start, out, N_CELLS);
    }
}

// Round 6
// 62.081 us; speedup vs baseline: 4.5074x; 1.0160x over previous
//
#include <hip/hip_runtime.h>

#define N_CELLS 100000
#define IN_CH 64
#define N_EDGES 1280000

// ---- bf16 helpers (bit-level, RNE) ----
__device__ __forceinline__ unsigned short f32_to_bf16(float f) {
    unsigned u = __float_as_uint(f);
    u += 0x7FFFu + ((u >> 16) & 1u);   // round to nearest even
    return (unsigned short)(u >> 16);
}
__device__ __forceinline__ float bf16_to_f32(unsigned short h) {
    return __uint_as_float((unsigned)h << 16);
}

#define SCORE_BLOCKS ((N_CELLS * 16 + 255) / 256)
#define ROWSTART_BLOCKS ((N_EDGES + 255) / 256)

// Fused kernel 1: blocks [0, SCORE_BLOCKS) compute per-cell scores + bf16 x copy;
// blocks [SCORE_BLOCKS, SCORE_BLOCKS+ROWSTART_BLOCKS) build CSR row offsets.
__global__ void __launch_bounds__(256) prep_kernel(
    const float* __restrict__ x, const float* __restrict__ w,
    const int* __restrict__ tgt,
    float* __restrict__ s_src, float* __restrict__ s_tgt,
    unsigned short* __restrict__ xb, int* __restrict__ row_start,
    int n_cells, int n_edges) {
    if (blockIdx.x < SCORE_BLOCKS) {
        int gid  = blockIdx.x * 256 + threadIdx.x;
        int wave = gid >> 6;
        int lane = threadIdx.x & 63;
        int grp  = lane >> 4;
        int sub  = lane & 15;
        int cell = wave * 4 + grp;

        float4 xv = make_float4(0.f, 0.f, 0.f, 0.f);
        if (cell < n_cells)
            xv = *(const float4*)&x[(((unsigned)cell << 6) | ((unsigned)sub << 2))];
        if (xb && cell < n_cells) {
            ushort4 hb;
            hb.x = f32_to_bf16(xv.x); hb.y = f32_to_bf16(xv.y);
            hb.z = f32_to_bf16(xv.z); hb.w = f32_to_bf16(xv.w);
            *(ushort4*)&xb[(((unsigned)cell << 6) | ((unsigned)sub << 2))] = hb;
        }
        const float4* w4 = (const float4*)w;
        float4 wa = w4[sub];
        float4 wb = w4[16 + sub];
        float a = xv.x * wa.x + xv.y * wa.y + xv.z * wa.z + xv.w * wa.w;
        float b = xv.x * wb.x + xv.y * wb.y + xv.z * wb.z + xv.w * wb.w;
#pragma unroll
        for (int off = 8; off; off >>= 1) {
            a += __shfl_xor(a, off, 64);
            b += __shfl_xor(b, off, 64);
        }
        if (sub == 0 && cell < n_cells) {
            s_src[cell] = a;
            s_tgt[cell] = b;
        }
    } else {
        int e = (blockIdx.x - SCORE_BLOCKS) * 256 + threadIdx.x;
        if (e >= n_edges) return;
        int lane = threadIdx.x & 63;
        int t = tgt[e];
        int prev = __shfl_up(t, 1, 64);
        if (lane == 0) prev = (e == 0) ? -1 : tgt[e - 1];
        for (int c = prev + 1; c <= t; ++c) row_start[c] = e;
        if (e == n_edges - 1) {
            for (int c = t + 1; c <= n_cells; ++c) row_start[c] = n_edges;
        }
    }
}

// Kernel 2 (bf16 gather): one 16-lane group per cell. After computing per-edge v,
// bitonic-sort the group's (src, v) pairs by src so gathers sweep the x-table in
// ascending order -> all co-resident waves sweep in sync -> L2-sized working set.
__global__ void __launch_bounds__(256) agg_kernel_bf16(
    const unsigned short* __restrict__ xb, const int* __restrict__ src,
    const float* __restrict__ nbhd,
    const float* __restrict__ s_src, const float* __restrict__ s_tgt,
    const int* __restrict__ row_start,
    float* __restrict__ out, int n_cells) {
    int gid  = blockIdx.x * blockDim.x + threadIdx.x;
    int lane = threadIdx.x & 63;
    int grp  = lane >> 4;
    int sub  = lane & 15;
    int cell = (gid >> 6) * 4 + grp;
    unsigned suboff = (unsigned)sub << 2;
    int gbase = grp << 4;

    int lo = 0, hi = 0;
    float sti = 0.f;
    if (cell < n_cells) {
        lo  = row_start[cell];
        hi  = row_start[cell + 1];
        sti = s_tgt[cell];
    }

    float4 acc = make_float4(0.f, 0.f, 0.f, 0.f);
    for (int base = lo; base < hi; base += 16) {
        int cnt = hi - base;
        if (cnt > 16) cnt = 16;
        int   key = 0x7FFFFFFF;   // inactive lanes sink to the end
        float v   = 0.f;
        if (sub < cnt) {
            int j = src[base + sub];
            float a = s_src[j] + sti;
            v = nbhd[base + sub] * (a > 0.f ? a : expm1f(a));
            key = j;
        }
        // in-group bitonic sort by key (strides <= 8 stay within the 16-lane group)
#pragma unroll
        for (int size = 2; size <= 16; size <<= 1) {
#pragma unroll
            for (int strd = size >> 1; strd > 0; strd >>= 1) {
                int   pk = __shfl_xor(key, strd, 64);
                float pv = __shfl_xor(v,   strd, 64);
                bool takeMin = ((sub & size) == 0) == ((sub & strd) == 0);
                bool sw = takeMin ? (pk < key) : (pk > key);
                if (sw) { key = pk; v = pv; }
            }
        }
        int j = key;
        int t = 0;
        for (; t + 4 <= cnt; t += 4) {
            int   j0 = __shfl(j, gbase + t,     64);
            int   j1 = __shfl(j, gbase + t + 1, 64);
            int   j2 = __shfl(j, gbase + t + 2, 64);
            int   j3 = __shfl(j, gbase + t + 3, 64);
            float v0 = __shfl(v, gbase + t,     64);
            float v1 = __shfl(v, gbase + t + 1, 64);
            float v2 = __shfl(v, gbase + t + 2, 64);
            float v3 = __shfl(v, gbase + t + 3, 64);
            ushort4 h0 = *(const ushort4*)&xb[(((unsigned)j0 << 6) | suboff)];
            ushort4 h1 = *(const ushort4*)&xb[(((unsigned)j1 << 6) | suboff)];
            ushort4 h2 = *(const ushort4*)&xb[(((unsigned)j2 << 6) | suboff)];
            ushort4 h3 = *(const ushort4*)&xb[(((unsigned)j3 << 6) | suboff)];
            acc.x = fmaf(v0, bf16_to_f32(h0.x), acc.x);
            acc.y = fmaf(v0, bf16_to_f32(h0.y), acc.y);
            acc.z = fmaf(v0, bf16_to_f32(h0.z), acc.z);
            acc.w = fmaf(v0, bf16_to_f32(h0.w), acc.w);
            acc.x = fmaf(v1, bf16_to_f32(h1.x), acc.x);
            acc.y = fmaf(v1, bf16_to_f32(h1.y), acc.y);
            acc.z = fmaf(v1, bf16_to_f32(h1.z), acc.z);
            acc.w = fmaf(v1, bf16_to_f32(h1.w), acc.w);
            acc.x = fmaf(v2, bf16_to_f32(h2.x), acc.x);
            acc.y = fmaf(v2, bf16_to_f32(h2.y), acc.y);
            acc.z = fmaf(v2, bf16_to_f32(h2.z), acc.z);
            acc.w = fmaf(v2, bf16_to_f32(h2.w), acc.w);
            acc.x = fmaf(v3, bf16_to_f32(h3.x), acc.x);
            acc.y = fmaf(v3, bf16_to_f32(h3.y), acc.y);
            acc.z = fmaf(v3, bf16_to_f32(h3.z), acc.z);
            acc.w = fmaf(v3, bf16_to_f32(h3.w), acc.w);
        }
        for (; t < cnt; ++t) {
            int   jt = __shfl(j, gbase + t, 64);
            float vt = __shfl(v, gbase + t, 64);
            ushort4 ht = *(const ushort4*)&xb[(((unsigned)jt << 6) | suboff)];
            acc.x = fmaf(vt, bf16_to_f32(ht.x), acc.x);
            acc.y = fmaf(vt, bf16_to_f32(ht.y), acc.y);
            acc.z = fmaf(vt, bf16_to_f32(ht.z), acc.z);
            acc.w = fmaf(vt, bf16_to_f32(ht.w), acc.w);
        }
    }
    if (cell < n_cells)
        *(float4*)&out[(((unsigned)cell << 6) | suboff)] = acc;
}

// Fallback f32-gather version (used only if workspace is too small for xb).
__global__ void __launch_bounds__(256) agg_kernel_f32(
    const float* __restrict__ x, const int* __restrict__ src,
    const float* __restrict__ nbhd,
    const float* __restrict__ s_src, const float* __restrict__ s_tgt,
    const int* __restrict__ row_start,
    float* __restrict__ out, int n_cells) {
    int gid  = blockIdx.x * blockDim.x + threadIdx.x;
    int lane = threadIdx.x & 63;
    int grp  = lane >> 4;
    int sub  = lane & 15;
    int cell = (gid >> 6) * 4 + grp;
    unsigned suboff = (unsigned)sub << 2;
    int gbase = grp << 4;

    int lo = 0, hi = 0;
    float sti = 0.f;
    if (cell < n_cells) {
        lo  = row_start[cell];
        hi  = row_start[cell + 1];
        sti = s_tgt[cell];
    }
    float4 acc = make_float4(0.f, 0.f, 0.f, 0.f);
    for (int base = lo; base < hi; base += 16) {
        int cnt = hi - base;
        if (cnt > 16) cnt = 16;
        int   j = 0;
        float v = 0.f;
        if (sub < cnt) {
            j = src[base + sub];
            float a = s_src[j] + sti;
            v = nbhd[base + sub] * (a > 0.f ? a : expm1f(a));
        }
        for (int t = 0; t < cnt; ++t) {
            int   jt = __shfl(j, gbase + t, 64);
            float vt = __shfl(v, gbase + t, 64);
            float4 xt = *(const float4*)&x[(((unsigned)jt << 6) | suboff)];
            acc.x = fmaf(vt, xt.x, acc.x); acc.y = fmaf(vt, xt.y, acc.y);
            acc.z = fmaf(vt, xt.z, acc.z); acc.w = fmaf(vt, xt.w, acc.w);
        }
    }
    if (cell < n_cells)
        *(float4*)&out[(((unsigned)cell << 6) | suboff)] = acc;
}

extern "C" void kernel_launch(void* const* d_in, const int* in_sizes, int n_in,
                              void* d_out, int out_size, void* d_ws, size_t ws_size,
                              hipStream_t stream) {
    const float* x    = (const float*)d_in[0];   // [N_CELLS, 64]
    const float* w    = (const float*)d_in[1];   // [128]
    const float* nbhd = (const float*)d_in[2];   // [N_EDGES]
    const int*   tgt  = (const int*)d_in[3];     // [N_EDGES] sorted
    const int*   src  = (const int*)d_in[4];     // [N_EDGES]
    float*       out  = (float*)d_out;           // [N_CELLS, 64]

    // workspace layout
    float* s_src     = (float*)d_ws;                       // N_CELLS f32
    float* s_tgt     = s_src + N_CELLS;                    // N_CELLS f32
    int*   row_start = (int*)(s_tgt + N_CELLS);            // N_CELLS+1 i32
    unsigned short* xb = (unsigned short*)(row_start + N_CELLS + 1);  // N_CELLS*64 bf16
    size_t need_bf16 = (size_t)(2 * N_CELLS + N_CELLS + 1) * 4 + (size_t)N_CELLS * IN_CH * 2;
    bool use_bf16 = ws_size >= need_bf16;

    {
        int blocks = SCORE_BLOCKS + ROWSTART_BLOCKS;
        prep_kernel<<<blocks, 256, 0, stream>>>(x, w, tgt, s_src, s_tgt,
                                                use_bf16 ? xb : (unsigned short*)nullptr,
                                                row_start, N_CELLS, N_EDGES);
    }
    {
        int threads = 256;
        int blocks  = (N_CELLS * 16 + threads - 1) / threads;
        if (use_bf16)
            agg_kernel_bf16<<<blocks, threads, 0, stream>>>(xb, src, nbhd, s_src, s_tgt,
                                                            row_start, out, N_CELLS);
        else
            agg_kernel_f32<<<blocks, threads, 0, stream>>>(x, src, nbhd, s_src, s_tgt,
                                                           row_start, out, N_CELLS);
    }
}